// Round 5
// baseline (103.774 us; speedup 1.0000x reference)
//
#include <hip/hip_runtime.h>
#include <hip/hip_cooperative_groups.h>
#include <math.h>

namespace cg = cooperative_groups;

#define NIMG 24        // B*C = 8*3
#define H    256
#define W    256
#define NPIX (H * W)
#define NROWS (NIMG * H)           // 6144
#define GRID 256
#define BLK  256
#define WPB  (BLK / 64)            // 4 waves per block
#define NWAVE (GRID * WPB)         // 1024
#define ROWS_PER_WAVE (NROWS / NWAVE)   // 6
#define NTASK (NIMG * (W / 4))     // 1536 column-group tasks (img, 4 cols)
#define TASKS_PER_BLK (NTASK / GRID)    // 6
#define BIGF 1.0e6f

// ---------------------------------------------------------------------------
// Wave-level inclusive max scans (64 lanes)
// ---------------------------------------------------------------------------
__device__ __forceinline__ float wscan_fwd_max(float v, int lane) {
#pragma unroll
    for (int off = 1; off < 64; off <<= 1) {
        float u = __shfl_up(v, off, 64);
        if (lane >= off) v = fmaxf(v, u);
    }
    return v;
}
__device__ __forceinline__ float wscan_rev_max(float v, int lane) {
#pragma unroll
    for (int off = 1; off < 64; off <<= 1) {
        float u = __shfl_down(v, off, 64);
        if (lane + off < 64) v = fmaxf(v, u);
    }
    return v;
}

// ---------------------------------------------------------------------------
// Single fused cooperative kernel:
//  phase 1: row EDT (wave per row, lane owns 4 cols) -> f = g_pos - g_neg
//  grid.sync()
//  phase 2: window-bounded exact column min-plus + sigmoid*d, per-block
//           double partial (fixed order, no atomics)
//  grid.sync()
//  phase 3: block 0 reduces 256 partials -> mean -> out
// ---------------------------------------------------------------------------
__global__ void boundary_fused_kernel(const int* __restrict__ tgt,
                                      const float* __restrict__ pred,
                                      float* __restrict__ fbuf,
                                      double* __restrict__ partials,
                                      float* __restrict__ out) {
    cg::grid_group grid = cg::this_grid();
    const int t    = threadIdx.x;
    const int lane = t & 63;
    const int wid  = t >> 6;
    const int bid  = blockIdx.x;

    // ---------------- phase 1: row EDT ----------------
    const float c0 = (float)(lane << 2);
    const float c1 = c0 + 1.0f, c2 = c0 + 2.0f, c3 = c0 + 3.0f;
#pragma unroll
    for (int s = 0; s < ROWS_PER_WAVE; ++s) {
        const int gw  = bid * WPB + wid + s * NWAVE;  // row id 0..6143
        const int img = gw >> 8;
        const int row = gw & 255;
        const int4 tv = ((const int4*)(tgt + (img << 16) + (row << 8)))[lane];

        auto polarity = [&](bool z0, bool z1, bool z2, bool z3) -> float4 {
            float a0 = z0 ? c0 : -BIGF;
            float a1 = fmaxf(z1 ? c1 : -BIGF, a0);
            float a2 = fmaxf(z2 ? c2 : -BIGF, a1);
            float a3 = fmaxf(z3 ? c3 : -BIGF, a2);
            float sm = wscan_fwd_max(a3, lane);
            float ex = __shfl_up(sm, 1, 64);
            if (lane == 0) ex = -BIGF;
            float b3 = z3 ? -c3 : -BIGF;
            float b2 = fmaxf(z2 ? -c2 : -BIGF, b3);
            float b1 = fmaxf(z1 ? -c1 : -BIGF, b2);
            float b0 = fmaxf(z0 ? -c0 : -BIGF, b1);
            float sr  = wscan_rev_max(b0, lane);
            float exr = __shfl_down(sr, 1, 64);
            if (lane == 63) exr = -BIGF;

            float l0 = fmaxf(ex, a0), l1 = fmaxf(ex, a1);
            float l2 = fmaxf(ex, a2), l3 = fmaxf(ex, a3);
            float n0 = fmaxf(exr, b0), n1 = fmaxf(exr, b1);
            float n2 = fmaxf(exr, b2), n3 = fmaxf(exr, b3);

            float4 g;
            g.x = fminf(fminf(c0 - l0, -n0 - c0), BIGF);
            g.y = fminf(fminf(c1 - l1, -n1 - c1), BIGF);
            g.z = fminf(fminf(c2 - l2, -n2 - c2), BIGF);
            g.w = fminf(fminf(c3 - l3, -n3 - c3), BIGF);
            return g;
        };

        const float4 gp = polarity(tv.x == 0, tv.y == 0, tv.z == 0, tv.w == 0);
        const float4 gn = polarity(tv.x != 0, tv.y != 0, tv.z != 0, tv.w != 0);
        float4 o;
        o.x = gp.x - gn.x;  o.y = gp.y - gn.y;
        o.z = gp.z - gn.z;  o.w = gp.w - gn.w;
        ((float4*)(fbuf + (img << 16) + (row << 8)))[lane] = o;
    }

    grid.sync();

    // ---------------- phase 2: column min-plus ----------------
    __shared__ float sf[4][264];
    __shared__ float sp[4][264];
    double acc = 0.0;

    for (int s = 0; s < TASKS_PER_BLK; ++s) {
        const int tg  = bid + s * GRID;       // 0..1535
        const int img = tg >> 6;
        const int j0  = (tg & 63) << 2;

        __syncthreads();                       // protect LDS reuse
        {
            const int base = (img << 16) + (t << 8) + j0;
            const float4 fv = *(const float4*)(fbuf + base);
            const float4 pv = *(const float4*)(pred + base);
            sf[0][t] = fv.x; sf[1][t] = fv.y; sf[2][t] = fv.z; sf[3][t] = fv.w;
            sp[0][t] = pv.x; sp[1][t] = pv.y; sp[2][t] = pv.z; sp[3][t] = pv.w;
        }
        __syncthreads();

        const float* sc = sf[wid];             // wave-uniform column base
        const float* pc = sp[wid];

        float v0 = sc[lane], v1 = sc[lane + 64];
        float v2 = sc[lane + 128], v3 = sc[lane + 192];
        const bool colempty =
            __all(v0 == -BIGF && v1 == -BIGF && v2 == -BIGF && v3 == -BIGF);

        if (!colempty) {
            float vq[4] = {v0, v1, v2, v3};
#pragma unroll
            for (int q = 0; q < 4; ++q) {
                const int i = lane + (q << 6);
                const float fv = vq[q];
                const bool  m  = fv > 0.0f;    // sign(f) = pixel polarity
                const float sgn = m ? 1.0f : -1.0f;
                const float gi = fabsf(fv);
                const int  gii = (int)gi;
                const int  lo  = (i - gii) > 0 ? (i - gii) : 0;
                const int  hi  = (i + gii) < (H - 1) ? (i + gii) : (H - 1);
                const float fi = (float)i;

                float dm = 3.0e38f;
                float dk = fi - (float)lo;
                for (int k = lo; k <= hi; ++k) {
                    const float g = fmaxf(sgn * sc[k], 0.0f);
                    dm = fminf(dm, fmaf(g, g, dk * dk));
                    dk -= 1.0f;
                }

                const float d = m ? sqrtf(dm) : -sqrtf(dm);
                const float p = pc[i];
                const float sig = 1.0f / (1.0f + expf(-p));
                acc += (double)sig * (double)d;
            }
        }
    }

    // block reduction -> per-block partial (fixed order)
#pragma unroll
    for (int off = 32; off > 0; off >>= 1) acc += __shfl_down(acc, off, 64);
    __shared__ double wsum[WPB];
    if (lane == 0) wsum[wid] = acc;
    __syncthreads();
    if (t == 0) partials[bid] = (wsum[0] + wsum[1]) + (wsum[2] + wsum[3]);

    grid.sync();

    // ---------------- phase 3: final reduction ----------------
    if (bid == 0) {
        __shared__ double sred[BLK];
        sred[t] = partials[t];                 // GRID == BLK == 256
        __syncthreads();
#pragma unroll
        for (int off = BLK / 2; off > 0; off >>= 1) {
            if (t < off) sred[t] += sred[t + off];
            __syncthreads();
        }
        if (t == 0) out[0] = (float)(sred[0] / (double)(NIMG * NPIX));
    }
}

extern "C" void kernel_launch(void* const* d_in, const int* in_sizes, int n_in,
                              void* d_out, int out_size, void* d_ws, size_t ws_size,
                              hipStream_t stream) {
    const int*   tgt  = (const int*)d_in[1];
    const float* pred = (const float*)d_in[0];
    float* out = (float*)d_out;

    char* ws = (char*)d_ws;
    const size_t fbytes = (size_t)NIMG * NPIX * sizeof(float);   // 6,291,456 B
    float*  fbuf     = (float*)(ws);
    double* partials = (double*)(ws + fbytes);                   // 256 * 8 B

    void* args[] = { (void*)&tgt, (void*)&pred, (void*)&fbuf,
                     (void*)&partials, (void*)&out };
    hipLaunchCooperativeKernel((const void*)boundary_fused_kernel,
                               dim3(GRID), dim3(BLK), args, 0, stream);
}

// Round 6
// 36.984 us; speedup vs baseline: 2.8059x; 2.8059x over previous
//
#include <hip/hip_runtime.h>
#include <math.h>

#define NIMG 24        // B*C = 8*3
#define H    256
#define W    256
#define NPIX (H * W)
#define NROWS (NIMG * H)
#define CPB  32                    // columns per pass-2 block
#define NBLK2 (NIMG * (W / CPB))   // 192
#define BIGF 1.0e6f

// ---------------------------------------------------------------------------
// Wave-level inclusive max scans (64 lanes)
// ---------------------------------------------------------------------------
__device__ __forceinline__ float wscan_fwd_max(float v, int lane) {
#pragma unroll
    for (int off = 1; off < 64; off <<= 1) {
        float u = __shfl_up(v, off, 64);
        if (lane >= off) v = fmaxf(v, u);
    }
    return v;
}
__device__ __forceinline__ float wscan_rev_max(float v, int lane) {
#pragma unroll
    for (int off = 1; off < 64; off <<= 1) {
        float u = __shfl_down(v, off, 64);
        if (lane + off < 64) v = fmaxf(v, u);
    }
    return v;
}

// ---------------------------------------------------------------------------
// Pass 1: one WAVE per row (lane owns 4 cols). 1-D EDT both polarities via
// per-lane prefix + wave shfl-scan. Output: f = g_pos - g_neg (exactly one
// is nonzero per pixel; sign(f) = polarity). Coalesced float4 stores.
// No atomics (r3 lesson: same-line device atomics serialize at ~23ns).
// ---------------------------------------------------------------------------
__global__ void edt_rows_kernel(const int* __restrict__ tgt,
                                float* __restrict__ f) {
    const int tid  = blockIdx.x * 256 + threadIdx.x;
    const int gw   = tid >> 6;          // global wave id == row id
    const int lane = tid & 63;
    const int img  = gw >> 8;
    const int row  = gw & 255;

    const int4 tv = ((const int4*)(tgt + (img << 16) + (row << 8)))[lane];
    const float c0 = (float)(lane << 2);
    const float c1 = c0 + 1.0f, c2 = c0 + 2.0f, c3 = c0 + 3.0f;

    auto polarity = [&](bool z0, bool z1, bool z2, bool z3) -> float4 {
        float a0 = z0 ? c0 : -BIGF;
        float a1 = fmaxf(z1 ? c1 : -BIGF, a0);
        float a2 = fmaxf(z2 ? c2 : -BIGF, a1);
        float a3 = fmaxf(z3 ? c3 : -BIGF, a2);
        float s  = wscan_fwd_max(a3, lane);
        float ex = __shfl_up(s, 1, 64);
        if (lane == 0) ex = -BIGF;
        float b3 = z3 ? -c3 : -BIGF;
        float b2 = fmaxf(z2 ? -c2 : -BIGF, b3);
        float b1 = fmaxf(z1 ? -c1 : -BIGF, b2);
        float b0 = fmaxf(z0 ? -c0 : -BIGF, b1);
        float sr  = wscan_rev_max(b0, lane);
        float exr = __shfl_down(sr, 1, 64);
        if (lane == 63) exr = -BIGF;

        float l0 = fmaxf(ex, a0), l1 = fmaxf(ex, a1);
        float l2 = fmaxf(ex, a2), l3 = fmaxf(ex, a3);
        float n0 = fmaxf(exr, b0), n1 = fmaxf(exr, b1);
        float n2 = fmaxf(exr, b2), n3 = fmaxf(exr, b3);

        float4 g;
        g.x = fminf(fminf(c0 - l0, -n0 - c0), BIGF);
        g.y = fminf(fminf(c1 - l1, -n1 - c1), BIGF);
        g.z = fminf(fminf(c2 - l2, -n2 - c2), BIGF);
        g.w = fminf(fminf(c3 - l3, -n3 - c3), BIGF);
        return g;
    };

    const float4 gp = polarity(tv.x == 0, tv.y == 0, tv.z == 0, tv.w == 0);
    const float4 gn = polarity(tv.x != 0, tv.y != 0, tv.z != 0, tv.w != 0);
    float4 out;
    out.x = gp.x - gn.x;  out.y = gp.y - gn.y;
    out.z = gp.z - gn.z;  out.w = gp.w - gn.w;
    ((float4*)(f + (img << 16) + (row << 8)))[lane] = out;
}

// ---------------------------------------------------------------------------
// Pass 2: block = (img, 32-column group). Full 256x32 f-tile staged in LDS
// via COALESCED row-segment float4 loads (no fetch amplification — r5
// lesson: the 1KB-stride column reads were a 4x over-fetch). Thread owns
// one column x 32 rows; window-bounded exact min-plus:
//   D2[i] = min_{|k-i| <= g[i]} g_m[k]^2 + (i-k)^2
// (minimizer must satisfy |i-k| <= g[i] since k=i gives g[i]^2). All finite
// terms are exact fp32 integers -> bitwise equal to full scan.
// Image-empty flag in-block: image empty <=> staged tile is all -BIG
// (any nonempty row makes f != -BIG in every column).
// ---------------------------------------------------------------------------
__global__ void edt_cols_kernel(const float* __restrict__ f,
                                const float* __restrict__ pred,
                                double* __restrict__ partials) {
    const int blk  = blockIdx.x;          // img*8 + jg
    const int img  = blk >> 3;
    const int j0   = (blk & 7) << 5;
    const int t    = threadIdx.x;
    const int lane = t & 63;
    const int wid  = t >> 6;

    __shared__ float sf[H][CPB];          // 32 KB
    __shared__ int nonempty;
    if (t == 0) nonempty = 0;

    bool myne = false;
#pragma unroll
    for (int s = 0; s < 8; ++s) {
        const int idx = t + (s << 8);     // 0..2047 float4-chunks
        const int row = idx >> 3;
        const int q   = (idx & 7) << 2;   // float offset within row
        const float4 v = *(const float4*)(f + (img << 16) + (row << 8) + j0 + q);
        sf[row][q] = v.x; sf[row][q + 1] = v.y;
        sf[row][q + 2] = v.z; sf[row][q + 3] = v.w;
        myne = myne || (v.x != -BIGF) || (v.y != -BIGF) ||
                       (v.z != -BIGF) || (v.w != -BIGF);
    }
    __syncthreads();                      // tile ready; nonempty=0 ordered
    if (myne) nonempty = 1;               // benign race, all write 1
    __syncthreads();
    const int flag = nonempty;

    const int c  = t & 31;                // own column within tile
    const int r0 = (t >> 5) << 5;         // own 32-row band
    double acc = 0.0;
#pragma unroll 4
    for (int ii = 0; ii < 32; ++ii) {
        const int i = r0 + ii;
        const float fv = sf[i][c];
        const bool  m  = fv > 0.0f;       // sign(f) = pixel polarity
        const float sgn = m ? 1.0f : -1.0f;
        const float gi = fabsf(fv);
        const int  gii = (int)gi;
        int lo = i - gii; lo = lo > 0 ? lo : 0;
        int hi = i + gii; hi = hi < (H - 1) ? hi : (H - 1);

        float dm = 3.0e38f;
        float dk = (float)(i - lo);
        for (int k = lo; k <= hi; ++k) {
            const float g = fmaxf(sgn * sf[k][c], 0.0f);  // needed polarity
            dm = fminf(dm, fmaf(g, g, dk * dk));
            dk -= 1.0f;
        }

        float d = m ? sqrtf(dm) : -sqrtf(dm);
        if (!flag) d = 0.0f;
        const float p = pred[(img << 16) + (i << 8) + j0 + c];
        const float sig = 1.0f / (1.0f + expf(-p));
        acc += (double)sig * (double)d;
    }

    // wave reduce (double), then 4 wave sums -> per-block partial
#pragma unroll
    for (int off = 32; off > 0; off >>= 1) acc += __shfl_down(acc, off, 64);
    __shared__ double wsum[4];
    if (lane == 0) wsum[wid] = acc;
    __syncthreads();
    if (t == 0) partials[blk] = (wsum[0] + wsum[1]) + (wsum[2] + wsum[3]);
}

// ---------------------------------------------------------------------------
// Finalize: deterministic sum of 192 partials -> mean -> fp32
// ---------------------------------------------------------------------------
__global__ void finalize_kernel(const double* __restrict__ partials,
                                float* __restrict__ out) {
    const int tid = threadIdx.x;
    __shared__ double sred[256];
    sred[tid] = (tid < NBLK2) ? partials[tid] : 0.0;
    __syncthreads();
    for (int off = 128; off > 0; off >>= 1) {
        if (tid < off) sred[tid] += sred[tid + off];
        __syncthreads();
    }
    if (tid == 0) out[0] = (float)(sred[0] / (double)(NIMG * NPIX));
}

extern "C" void kernel_launch(void* const* d_in, const int* in_sizes, int n_in,
                              void* d_out, int out_size, void* d_ws, size_t ws_size,
                              hipStream_t stream) {
    const float* pred = (const float*)d_in[0];
    const int*   tgt  = (const int*)d_in[1];
    float* out = (float*)d_out;

    char* ws = (char*)d_ws;
    const size_t fbytes = (size_t)NIMG * NPIX * sizeof(float);   // 6,291,456 B
    float*  fbuf     = (float*)(ws);
    double* partials = (double*)(ws + fbytes);                   // 192 * 8 B

    edt_rows_kernel<<<NROWS / 4, 256, 0, stream>>>(tgt, fbuf);
    edt_cols_kernel<<<NBLK2, 256, 0, stream>>>(fbuf, pred, partials);
    finalize_kernel<<<1, 256, 0, stream>>>(partials, out);
}